// Round 7
// baseline (607.099 us; speedup 1.0000x reference)
//
#include <hip/hip_runtime.h>
#include <hip/hip_bf16.h>
#include <cmath>
#include <stdint.h>

#define B_ 4
#define M_ 1024
#define N_ 2048
#define D_ 1024
#define H_ 16
#define DH_ 64
#define NT 64      // N tile
#define NTQ 8      // tiles per quarter (N split 4-way inside the block)
#define PITCH 72   // prep LDS pitch (bf16)

typedef __bf16 bf16_t;
typedef __attribute__((ext_vector_type(8))) __bf16 bf16x8;
typedef __attribute__((ext_vector_type(16))) float f32x16;
typedef __attribute__((ext_vector_type(2))) float f32x2;

static __device__ __forceinline__ float silu_f(float x) {
  return x / (1.0f + __expf(-x));
}

// pack two f32 -> two bf16 in one u32 (v_cvt_pk_bf16_f32)
static __device__ __forceinline__ unsigned pk2(float a, float b) {
  union { __bf16 h[2]; unsigned u; } p;
  p.h[0] = (__bf16)a; p.h[1] = (__bf16)b;
  return p.u;
}

// swap bits 2 and 3 of a row index (involution) — K-row permutation so the
// QK^T C-layout registers land directly in PV B-fragment order.
static __device__ __forceinline__ int sw23(int x) {
  return (x & ~12) | ((x & 4) << 1) | ((x & 8) >> 1);
}

// ---- prep ---- (unchanged from r6, verified)
// K' = L2norm(silu(kv heads)), ZEROED for masked n, in MFMA A-FRAGMENT order:
//   kp elem addr = bh*131072 + (tile*8 + nb*4 + kk)*512 + (hi*32+sw23(l31))*8+j
// V^T (raw kv heads), ZEROED for masked n, ALSO in A-fragment order:
//   vt elem addr = bh*131072 + (tile*8 + i*4 + ks)*512 + (hi*32+l31)*8 + j
// attn loads every fragment as ONE coalesced dwordx4 per lane.
__global__ __launch_bounds__(256) void prep_kernel(
    const float* __restrict__ kv, const int* __restrict__ kv_mask,
    bf16_t* __restrict__ kp, bf16_t* __restrict__ vt,
    unsigned long long* __restrict__ mb) {
  __shared__ __align__(16) bf16_t Lt[NT][PITCH];
  const int bx = blockIdx.x;
  const int hp = bx & 7;
  const int nt = (bx >> 3) & 31;
  const int b  = bx >> 8;
  const int n0 = nt * NT;
  const int tid = threadIdx.x;
  const float keep = kv_mask[b * N_ + n0 + (tid >> 2)] ? 0.f : 1.f;

  #pragma unroll
  for (int hi = 0; hi < 2; ++hi) {
    const int h = hp * 2 + hi;
    const size_t bh = (size_t)(b * H_ + h);
    {
      const int r = tid >> 2, c0 = (tid & 3) * 16;
      const float* src = kv + ((size_t)(b * N_ + n0 + r)) * D_ + h * DH_ + c0;
      union { float f[16]; float4 v4[4]; } raw;
      raw.v4[0] = *(const float4*)(src + 0);
      raw.v4[1] = *(const float4*)(src + 4);
      raw.v4[2] = *(const float4*)(src + 8);
      raw.v4[3] = *(const float4*)(src + 12);
      float sv[16];
      float ss = 0.f;
      #pragma unroll
      for (int i = 0; i < 16; ++i) { sv[i] = silu_f(raw.f[i]); ss += sv[i] * sv[i]; }
      ss += __shfl_xor(ss, 1); ss += __shfl_xor(ss, 2);
      const float inv = keep / fmaxf(sqrtf(ss), 1e-6f);  // 0 for masked rows
      union { bf16_t bs[16]; uint4 u[2]; } pk;
      #pragma unroll
      for (int i = 0; i < 16; ++i) pk.bs[i] = (bf16_t)(sv[i] * inv);
      // fragment-order K' write: kk = tid&3, nb = r>>5, lane-row sw23(r&31)
      const size_t fbase = bh * 131072 +
          (size_t)((nt * 8 + (r >> 5) * 4 + (tid & 3)) * 512 + sw23(r & 31) * 8);
      *(uint4*)(kp + fbase)       = pk.u[0];   // hi = 0 (d kk*16 + 0..7)
      *(uint4*)(kp + fbase + 256) = pk.u[1];   // hi = 1 (d kk*16 + 8..15)
      union { bf16_t bs[16]; uint4 u[2]; } pv;
      #pragma unroll
      for (int i = 0; i < 16; ++i) pv.bs[i] = (bf16_t)(raw.f[i] * keep);
      uint4* ldst = (uint4*)&Lt[r][c0];
      ldst[0] = pv.u[0]; ldst[1] = pv.u[1];
    }
    __syncthreads();
    {
      // V fragment-order write: thread (f = tid>>5, vl = tid&31) writes
      // lanes (vl, hi2) of frag f = (i<<2)|ks.
      const int f = tid >> 5;            // 0..7
      const int i_ = f >> 2, ks = f & 3;
      const int vl = tid & 31;
      const int d = i_ * 32 + vl;
      const size_t vbase = bh * 131072 + (size_t)((nt * 8 + f) * 512);
      #pragma unroll
      for (int hi2 = 0; hi2 < 2; ++hi2) {
        union { bf16_t bs[8]; uint4 u; } vp;
        #pragma unroll
        for (int j = 0; j < 8; ++j) vp.bs[j] = Lt[ks * 16 + hi2 * 8 + j][d];
        *(uint4*)(vt + vbase + (hi2 * 32 + vl) * 8) = vp.u;
      }
    }
    __syncthreads();
  }
  if (bx == 0 && tid < B_ * (N_ / 64)) {
    const int b2 = tid >> 5, tt = tid & 31;
    unsigned long long m = 0ull;
    for (int i = 0; i < 64; ++i)
      if (kv_mask[b2 * N_ + tt * 64 + i]) m |= (1ull << i);
    mb[tid] = m;
  }
}

// ---- main: flash cross-attn, 32x32x16 MFMA, register-direct K/V fragment
//      streams (no LDS/barriers in the loop). NEW: 4-way N-split — block =
//      2 q-groups x 4 N-quarters = 8 waves over 64 q-rows; grid 1024 blocks
//      -> 4 blocks/CU, 32 waves/CU nominal (2x the TLP of r2-r6, which sat
//      at 4 waves/SIMD and ~33% occupancy while every pipe idled <40% —
//      the latency-bound signature). va0 issue hoisted to tile start
//      (~400 cyc QK+softmax cover vs ~0 before). VGPR pinned <=64 via
//      __launch_bounds__(512,8). Epilogue: 4-partial sum combine. ----
__global__ __launch_bounds__(512, 8) void attn_kernel(
    const float* __restrict__ q, const bf16_t* __restrict__ kp,
    const bf16_t* __restrict__ vt, const unsigned long long* __restrict__ mb,
    float* __restrict__ out) {
  // epilogue-only LDS: O^T partials [64 d][65 pad] f32 + l [64] f32
  __shared__ __align__(1024) char smem[16896];

  const int tid  = threadIdx.x;
  const int w    = tid >> 6;     // 0..7
  const int wq   = w & 1;        // q-row group (2 x 32 rows)
  const int qtr  = w >> 1;       // N-quarter (4 x 512 n)
  const int lane = tid & 63;
  const int l31  = lane & 31;
  const int hi   = lane >> 5;

  // bijective XCD swizzle (1024 wgs % 8 == 0)
  const int wg = (blockIdx.x & 7) * 128 + (blockIdx.x >> 3);
  const int bh = wg >> 4;
  const int m0 = (wg & 15) * 64;
  const int b = bh >> 4, h = bh & 15;

  // per-lane fragment bases (tile stride 4096 elems = 8 frags x 512;
  // quarter stride = 8 tiles x 4096)
  const bf16_t* kfb = kp + (size_t)bh * 131072 + (size_t)qtr * 32768
                         + (size_t)lane * 8;
  const bf16_t* vfb = vt + (size_t)bh * 131072 + (size_t)qtr * 32768
                         + (size_t)lane * 8;

  // prologue: ka(0)
  bf16x8 ka[2][4];
  #pragma unroll
  for (int nb = 0; nb < 2; ++nb)
    #pragma unroll
    for (int kk = 0; kk < 4; ++kk)
      ka[nb][kk] = *(const bf16x8*)(kfb + (nb * 4 + kk) * 512);

  // Q: 32 rows/wave straight to registers, pre-scaled by 1/8 (exact 2^-3)
  bf16x8 qb[4];
  {
    const float* qrow =
        q + ((size_t)(b * M_ + m0 + wq * 32 + l31)) * D_ + h * DH_ + hi * 8;
    float sv[32];
    float ss = 0.f;
    #pragma unroll
    for (int kk = 0; kk < 4; ++kk) {
      float4 a0 = *(const float4*)(qrow + kk * 16);
      float4 a1 = *(const float4*)(qrow + kk * 16 + 4);
      sv[kk * 8 + 0] = silu_f(a0.x); sv[kk * 8 + 1] = silu_f(a0.y);
      sv[kk * 8 + 2] = silu_f(a0.z); sv[kk * 8 + 3] = silu_f(a0.w);
      sv[kk * 8 + 4] = silu_f(a1.x); sv[kk * 8 + 5] = silu_f(a1.y);
      sv[kk * 8 + 6] = silu_f(a1.z); sv[kk * 8 + 7] = silu_f(a1.w);
      #pragma unroll
      for (int i = 0; i < 8; ++i) ss += sv[kk * 8 + i] * sv[kk * 8 + i];
    }
    ss += __shfl_xor(ss, 32);
    const float inv = 0.125f / fmaxf(sqrtf(ss), 1e-6f);
    #pragma unroll
    for (int kk = 0; kk < 4; ++kk) {
      union { unsigned u[4]; bf16x8 v; } pq;
      #pragma unroll
      for (int jj = 0; jj < 4; ++jj)
        pq.u[jj] = pk2(sv[kk * 8 + jj * 2] * inv, sv[kk * 8 + jj * 2 + 1] * inv);
      qb[kk] = pq.v;
    }
  }

  f32x16 o0, o1;
  #pragma unroll
  for (int r = 0; r < 16; ++r) { o0[r] = 0.f; o1[r] = 0.f; }
  float lrun = 0.f;
  unsigned cl = 0, ch = 0;  // masked-n counts for hi=0 / hi=1 lanes
  const unsigned long long* mbb = mb + b * (N_ / 64) + qtr * NTQ;

  #pragma unroll 1
  for (int tt = 0; tt < NTQ; ++tt) {
    // phantom-mass counts (uniform -> SALU popcount); with sw23 permutation
    // lane hi covers n bits {16c + 8*hi + 0..7}.
    const unsigned long long mk = mbb[tt];
    cl += (unsigned)__popcll(mk & 0x00FF00FF00FF00FFULL);
    ch += (unsigned)__popcll(mk & 0xFF00FF00FF00FF00ULL);

    // va i=0 issued at TILE START: QK + softmax (~400 cyc) covers L2 latency
    const bf16_t* vfp = vfb + (size_t)tt * 4096;
    bf16x8 va[4];
    #pragma unroll
    for (int ks = 0; ks < 4; ++ks)
      va[ks] = *(const bf16x8*)(vfp + ks * 512);

    bf16x8 pa[4];
    #pragma unroll
    for (int nb = 0; nb < 2; ++nb) {
      // S^T = K'(permuted) . Q'^T : col = l31 (m); reg r of lane hi is
      // n_phys = 16*(r>>3) + 8*hi + (r&7) within this nb 32-block
      f32x16 s;
      #pragma unroll
      for (int r = 0; r < 16; ++r) s[r] = 0.f;
      __builtin_amdgcn_s_setprio(1);
      #pragma unroll
      for (int kk = 0; kk < 4; ++kk)
        s = __builtin_amdgcn_mfma_f32_32x32x16_bf16(ka[nb][kk], qb[kk], s, 0, 0, 0);
      __builtin_amdgcn_s_setprio(0);

      // p = e^x ~= 1 + x + x^2/2 (|x| <= 1/8); poly(0) = 1 EXACTLY
      f32x2 p2[8];
      #pragma unroll
      for (int i = 0; i < 8; ++i) {
        f32x2 x; x.x = s[2 * i]; x.y = s[2 * i + 1];
        f32x2 u = x * 0.5f + 1.0f;
        p2[i] = x * u + 1.0f;
      }
      f32x2 t0 = (p2[0] + p2[1]) + (p2[2] + p2[3]);
      f32x2 t1 = (p2[4] + p2[5]) + (p2[6] + p2[7]);
      f32x2 ts = t0 + t1;
      lrun += ts.x + ts.y;

      // P registers ARE the PV B-fragment (sw23 baked into prep)
      union { unsigned u[4]; bf16x8 v; } f0, f1;
      #pragma unroll
      for (int jj = 0; jj < 4; ++jj) {
        f0.u[jj] = pk2(p2[jj].x, p2[jj].y);
        f1.u[jj] = pk2(p2[4 + jj].x, p2[4 + jj].y);
      }
      pa[nb * 2]     = f0.v;
      pa[nb * 2 + 1] = f1.v;
    }

    // ka prefetch for tile tt+1 (regs free after nb=1 QK)
    {
      const bf16_t* kn = kfb + (size_t)((tt + 1) & (NTQ - 1)) * 4096;
      #pragma unroll
      for (int nb = 0; nb < 2; ++nb)
        #pragma unroll
        for (int kk = 0; kk < 4; ++kk)
          ka[nb][kk] = *(const bf16x8*)(kn + (nb * 4 + kk) * 512);
    }

    // o0^T += V^T . P^T (d rows 0..31)
    __builtin_amdgcn_s_setprio(1);
    #pragma unroll
    for (int ks = 0; ks < 4; ++ks)
      o0 = __builtin_amdgcn_mfma_f32_32x32x16_bf16(va[ks], pa[ks], o0, 0, 0, 0);
    __builtin_amdgcn_s_setprio(0);

    // va i=1 (reuses va regs), then o1^T (d rows 32..63)
    #pragma unroll
    for (int ks = 0; ks < 4; ++ks)
      va[ks] = *(const bf16x8*)(vfp + (4 + ks) * 512);
    __builtin_amdgcn_s_setprio(1);
    #pragma unroll
    for (int ks = 0; ks < 4; ++ks)
      o1 = __builtin_amdgcn_mfma_f32_32x32x16_bf16(va[ks], pa[ks], o1, 0, 0, 0);
    __builtin_amdgcn_s_setprio(0);
  }

  // subtract phantom mass (p=1 per masked n, exact); fold hi halves.
  lrun -= (float)(hi ? ch : cl);
  lrun += __shfl_xor(lrun, 32);

  // ---- combine 4 quarters + transpose through LDS ----
  float* Ob = (float*)smem;                    // [64 d][65] f32 (padded)
  float* Lb = (float*)(smem + 16640);          // [64] f32

  __syncthreads();
  if (qtr == 0) {
    #pragma unroll
    for (int r = 0; r < 16; ++r) {
      const int d = (r & 3) + ((r >> 2) << 3) + (hi << 2);
      Ob[d * 65 + wq * 32 + l31]        = o0[r];
      Ob[(d + 32) * 65 + wq * 32 + l31] = o1[r];
    }
    if (hi == 0) Lb[wq * 32 + l31] = lrun;
  }
  #pragma unroll 1
  for (int qq = 1; qq < 4; ++qq) {
    __syncthreads();
    if (qtr == qq) {
      #pragma unroll
      for (int r = 0; r < 16; ++r) {
        const int d = (r & 3) + ((r >> 2) << 3) + (hi << 2);
        Ob[d * 65 + wq * 32 + l31]        += o0[r];
        Ob[(d + 32) * 65 + wq * 32 + l31] += o1[r];
      }
      if (hi == 0) Lb[wq * 32 + l31] += lrun;
    }
  }
  __syncthreads();
  // store: thread covers (m = tid>>3, d = (tid&7)*8 .. +7); coalesced
  {
    const int m = tid >> 3, dc = (tid & 7) * 8;
    const float lv = Lb[m];
    const float iv = lv > 0.f ? 1.0f / lv : 0.f;
    float* orow = out + ((size_t)(b * M_ + m0 + m)) * D_ + h * DH_ + dc;
    float4 v0, v1;
    v0.x = Ob[(dc + 0) * 65 + m] * iv;
    v0.y = Ob[(dc + 1) * 65 + m] * iv;
    v0.z = Ob[(dc + 2) * 65 + m] * iv;
    v0.w = Ob[(dc + 3) * 65 + m] * iv;
    v1.x = Ob[(dc + 4) * 65 + m] * iv;
    v1.y = Ob[(dc + 5) * 65 + m] * iv;
    v1.z = Ob[(dc + 6) * 65 + m] * iv;
    v1.w = Ob[(dc + 7) * 65 + m] * iv;
    *(float4*)(orow + 0) = v0;
    *(float4*)(orow + 4) = v1;
  }
}

extern "C" void kernel_launch(void* const* d_in, const int* in_sizes, int n_in,
                              void* d_out, int out_size, void* d_ws, size_t ws_size,
                              hipStream_t stream) {
  const float* q  = (const float*)d_in[0];
  const float* kv = (const float*)d_in[1];
  const int* kv_mask = (const int*)d_in[2];
  float* out = (float*)d_out;

  // ws layout: K' frags 16MB | V^T frags 16MB | maskbits 1KB
  bf16_t* kp = (bf16_t*)d_ws;
  bf16_t* vt = kp + (size_t)B_ * H_ * N_ * DH_;
  unsigned long long* mb =
      (unsigned long long*)((char*)d_ws + 2 * (size_t)B_ * H_ * N_ * DH_ * sizeof(bf16_t));

  prep_kernel<<<B_ * 32 * 8, 256, 0, stream>>>(kv, kv_mask, kp, vt, mb);
  attn_kernel<<<B_ * H_ * (M_ / 64), 512, 0, stream>>>(q, kp, vt, mb, out);
}

// Round 9
// 205.029 us; speedup vs baseline: 2.9610x; 2.9610x over previous
//
#include <hip/hip_runtime.h>
#include <hip/hip_bf16.h>
#include <cmath>
#include <stdint.h>

#define B_ 4
#define M_ 1024
#define N_ 2048
#define D_ 1024
#define H_ 16
#define DH_ 64
#define NT 64      // N tile
#define NTH 16     // tiles per half (N split 2-way inside the block)
#define PITCH 72   // prep LDS pitch (bf16)

typedef __bf16 bf16_t;
typedef __attribute__((ext_vector_type(8))) __bf16 bf16x8;
typedef __attribute__((ext_vector_type(16))) float f32x16;
typedef __attribute__((ext_vector_type(2))) float f32x2;

static __device__ __forceinline__ float silu_f(float x) {
  return x / (1.0f + __expf(-x));
}

// pack two f32 -> two bf16 in one u32 (v_cvt_pk_bf16_f32)
static __device__ __forceinline__ unsigned pk2(float a, float b) {
  union { __bf16 h[2]; unsigned u; } p;
  p.h[0] = (__bf16)a; p.h[1] = (__bf16)b;
  return p.u;
}

// swap bits 2 and 3 of a row index (involution) — K-row permutation so the
// QK^T C-layout registers land directly in PV B-fragment order.
static __device__ __forceinline__ int sw23(int x) {
  return (x & ~12) | ((x & 4) << 1) | ((x & 8) >> 1);
}

// ---- prep ---- (unchanged from r6, verified)
// K' = L2norm(silu(kv heads)), ZEROED for masked n, in MFMA A-FRAGMENT order:
//   kp elem addr = bh*131072 + (tile*8 + nb*4 + kk)*512 + (hi*32+sw23(l31))*8+j
// V^T (raw kv heads), ZEROED for masked n, ALSO in A-fragment order:
//   vt elem addr = bh*131072 + (tile*8 + i*4 + ks)*512 + (hi*32+l31)*8 + j
// attn loads every fragment as ONE coalesced dwordx4 per lane.
__global__ __launch_bounds__(256) void prep_kernel(
    const float* __restrict__ kv, const int* __restrict__ kv_mask,
    bf16_t* __restrict__ kp, bf16_t* __restrict__ vt,
    unsigned long long* __restrict__ mb) {
  __shared__ __align__(16) bf16_t Lt[NT][PITCH];
  const int bx = blockIdx.x;
  const int hp = bx & 7;
  const int nt = (bx >> 3) & 31;
  const int b  = bx >> 8;
  const int n0 = nt * NT;
  const int tid = threadIdx.x;
  const float keep = kv_mask[b * N_ + n0 + (tid >> 2)] ? 0.f : 1.f;

  #pragma unroll
  for (int hi = 0; hi < 2; ++hi) {
    const int h = hp * 2 + hi;
    const size_t bh = (size_t)(b * H_ + h);
    {
      const int r = tid >> 2, c0 = (tid & 3) * 16;
      const float* src = kv + ((size_t)(b * N_ + n0 + r)) * D_ + h * DH_ + c0;
      union { float f[16]; float4 v4[4]; } raw;
      raw.v4[0] = *(const float4*)(src + 0);
      raw.v4[1] = *(const float4*)(src + 4);
      raw.v4[2] = *(const float4*)(src + 8);
      raw.v4[3] = *(const float4*)(src + 12);
      float sv[16];
      float ss = 0.f;
      #pragma unroll
      for (int i = 0; i < 16; ++i) { sv[i] = silu_f(raw.f[i]); ss += sv[i] * sv[i]; }
      ss += __shfl_xor(ss, 1); ss += __shfl_xor(ss, 2);
      const float inv = keep / fmaxf(sqrtf(ss), 1e-6f);  // 0 for masked rows
      union { bf16_t bs[16]; uint4 u[2]; } pk;
      #pragma unroll
      for (int i = 0; i < 16; ++i) pk.bs[i] = (bf16_t)(sv[i] * inv);
      // fragment-order K' write: kk = tid&3, nb = r>>5, lane-row sw23(r&31)
      const size_t fbase = bh * 131072 +
          (size_t)((nt * 8 + (r >> 5) * 4 + (tid & 3)) * 512 + sw23(r & 31) * 8);
      *(uint4*)(kp + fbase)       = pk.u[0];   // hi = 0 (d kk*16 + 0..7)
      *(uint4*)(kp + fbase + 256) = pk.u[1];   // hi = 1 (d kk*16 + 8..15)
      union { bf16_t bs[16]; uint4 u[2]; } pv;
      #pragma unroll
      for (int i = 0; i < 16; ++i) pv.bs[i] = (bf16_t)(raw.f[i] * keep);
      uint4* ldst = (uint4*)&Lt[r][c0];
      ldst[0] = pv.u[0]; ldst[1] = pv.u[1];
    }
    __syncthreads();
    {
      // V fragment-order write: thread (f = tid>>5, vl = tid&31) writes
      // lanes (vl, hi2) of frag f = (i<<2)|ks.
      const int f = tid >> 5;            // 0..7
      const int i_ = f >> 2, ks = f & 3;
      const int vl = tid & 31;
      const int d = i_ * 32 + vl;
      const size_t vbase = bh * 131072 + (size_t)((nt * 8 + f) * 512);
      #pragma unroll
      for (int hi2 = 0; hi2 < 2; ++hi2) {
        union { bf16_t bs[8]; uint4 u; } vp;
        #pragma unroll
        for (int j = 0; j < 8; ++j) vp.bs[j] = Lt[ks * 16 + hi2 * 8 + j][d];
        *(uint4*)(vt + vbase + (hi2 * 32 + vl) * 8) = vp.u;
      }
    }
    __syncthreads();
  }
  if (bx == 0 && tid < B_ * (N_ / 64)) {
    const int b2 = tid >> 5, tt = tid & 31;
    unsigned long long m = 0ull;
    for (int i = 0; i < 64; ++i)
      if (kv_mask[b2 * N_ + tt * 64 + i]) m |= (1ull << i);
    mb[tid] = m;
  }
}

// ---- main: flash cross-attn, 32x32x16 MFMA, register-direct K/V fragment
//      streams (no LDS/barriers in the loop), 2-way N-split (r6 geometry —
//      4 waves/SIMD is the hard occupancy ceiling: 32 acc VGPRs/lane).
//      NEW vs r6: (1) per-wave STAGGERED tile ring (wave wq starts at tile
//      4*wq) — the 4 waves of a half stop phase-locking, so their vmcnt
//      stalls decorrelate and the SIMD interleaves them; (2) all 8 V frags
//      issued at TILE START (~500 cyc QK/softmax cover vs ~0); (3) zvec
//      C-operand (kills 32 v_mov/tile). Sums are order-independent => exact.
__global__ __launch_bounds__(512, 4) void attn_kernel(
    const float* __restrict__ q, const bf16_t* __restrict__ kp,
    const bf16_t* __restrict__ vt, const unsigned long long* __restrict__ mb,
    float* __restrict__ out) {
  // LDS only for the epilogue combine: O^T partials [64 d][128 m] + l [128]
  __shared__ __align__(1024) char smem[33280];

  const int tid  = threadIdx.x;
  const int w    = tid >> 6;     // 0..7
  const int wq   = w & 3;        // q-row group
  const int half = w >> 2;       // N-half
  const int lane = tid & 63;
  const int l31  = lane & 31;
  const int hi   = lane >> 5;

  // bijective XCD swizzle (512 wgs % 8 == 0)
  const int wg = (blockIdx.x & 7) * 64 + (blockIdx.x >> 3);
  const int bh = wg >> 3;
  const int m0 = (wg & 7) * 128;
  const int b = bh >> 4, h = bh & 15;

  // per-lane fragment bases (tile stride 4096 elems = 8 frags x 512)
  const bf16_t* kfb = kp + (size_t)bh * 131072 + (size_t)half * 65536
                         + (size_t)lane * 8;
  const bf16_t* vfb = vt + (size_t)bh * 131072 + (size_t)half * 65536
                         + (size_t)lane * 8;

  const int tst = wq * 4;  // stagger: wave's ring start within its half

  // prologue: ka at this wave's first tile
  bf16x8 ka[2][4];
  #pragma unroll
  for (int nb = 0; nb < 2; ++nb)
    #pragma unroll
    for (int kk = 0; kk < 4; ++kk)
      ka[nb][kk] = *(const bf16x8*)(kfb + (size_t)tst * 4096 + (nb * 4 + kk) * 512);

  // Q: 32 rows/wave straight to registers, pre-scaled by 1/8 (exact 2^-3)
  bf16x8 qb[4];
  {
    const float* qrow =
        q + ((size_t)(b * M_ + m0 + wq * 32 + l31)) * D_ + h * DH_ + hi * 8;
    float sv[32];
    float ss = 0.f;
    #pragma unroll
    for (int kk = 0; kk < 4; ++kk) {
      float4 a0 = *(const float4*)(qrow + kk * 16);
      float4 a1 = *(const float4*)(qrow + kk * 16 + 4);
      sv[kk * 8 + 0] = silu_f(a0.x); sv[kk * 8 + 1] = silu_f(a0.y);
      sv[kk * 8 + 2] = silu_f(a0.z); sv[kk * 8 + 3] = silu_f(a0.w);
      sv[kk * 8 + 4] = silu_f(a1.x); sv[kk * 8 + 5] = silu_f(a1.y);
      sv[kk * 8 + 6] = silu_f(a1.z); sv[kk * 8 + 7] = silu_f(a1.w);
      #pragma unroll
      for (int i = 0; i < 8; ++i) ss += sv[kk * 8 + i] * sv[kk * 8 + i];
    }
    ss += __shfl_xor(ss, 32);
    const float inv = 0.125f / fmaxf(sqrtf(ss), 1e-6f);
    #pragma unroll
    for (int kk = 0; kk < 4; ++kk) {
      union { unsigned u[4]; bf16x8 v; } pq;
      #pragma unroll
      for (int jj = 0; jj < 4; ++jj)
        pq.u[jj] = pk2(sv[kk * 8 + jj * 2] * inv, sv[kk * 8 + jj * 2 + 1] * inv);
      qb[kk] = pq.v;
    }
  }

  f32x16 o0, o1, zvec;
  #pragma unroll
  for (int r = 0; r < 16; ++r) { o0[r] = 0.f; o1[r] = 0.f; zvec[r] = 0.f; }
  float lrun = 0.f;
  unsigned cl = 0, ch = 0;  // masked-n counts for hi=0 / hi=1 lanes
  const unsigned long long* mbb = mb + b * (N_ / 64);

  #pragma unroll 1
  for (int t = 0; t < NTH; ++t) {
    const int tt = (t + tst) & 15;  // this wave's staggered tile index
    // phantom-mass counts (uniform -> SALU popcount); with sw23 permutation
    // lane hi covers n bits {16c + 8*hi + 0..7}.
    const unsigned long long mk = mbb[half * NTH + tt];
    cl += (unsigned)__popcll(mk & 0x00FF00FF00FF00FFULL);
    ch += (unsigned)__popcll(mk & 0xFF00FF00FF00FF00ULL);

    // ALL 8 V fragments issued at tile start: QK + softmax covers the latency
    const bf16_t* vfp = vfb + (size_t)tt * 4096;
    bf16x8 va0[4], va1[4];
    #pragma unroll
    for (int ks = 0; ks < 4; ++ks) {
      va0[ks] = *(const bf16x8*)(vfp + ks * 512);
      va1[ks] = *(const bf16x8*)(vfp + (4 + ks) * 512);
    }

    bf16x8 pa[4];
    #pragma unroll
    for (int nb = 0; nb < 2; ++nb) {
      // S^T = K'(permuted) . Q'^T : col = l31 (m); reg r of lane hi is
      // n_phys = 16*(r>>3) + 8*hi + (r&7) within this nb 32-block
      __builtin_amdgcn_s_setprio(1);
      f32x16 s = __builtin_amdgcn_mfma_f32_32x32x16_bf16(
          ka[nb][0], qb[0], zvec, 0, 0, 0);
      #pragma unroll
      for (int kk = 1; kk < 4; ++kk)
        s = __builtin_amdgcn_mfma_f32_32x32x16_bf16(ka[nb][kk], qb[kk], s, 0, 0, 0);
      __builtin_amdgcn_s_setprio(0);

      // p = e^x ~= 1 + x + x^2/2 (|x| <= 1/8); poly(0) = 1 EXACTLY
      f32x2 p2[8];
      #pragma unroll
      for (int i = 0; i < 8; ++i) {
        f32x2 x; x.x = s[2 * i]; x.y = s[2 * i + 1];
        f32x2 u = x * 0.5f + 1.0f;
        p2[i] = x * u + 1.0f;
      }
      f32x2 t0 = (p2[0] + p2[1]) + (p2[2] + p2[3]);
      f32x2 t1 = (p2[4] + p2[5]) + (p2[6] + p2[7]);
      f32x2 ts = t0 + t1;
      lrun += ts.x + ts.y;

      // P registers ARE the PV B-fragment (sw23 baked into prep)
      union { unsigned u[4]; bf16x8 v; } f0, f1;
      #pragma unroll
      for (int jj = 0; jj < 4; ++jj) {
        f0.u[jj] = pk2(p2[jj].x, p2[jj].y);
        f1.u[jj] = pk2(p2[4 + jj].x, p2[4 + jj].y);
      }
      pa[nb * 2]     = f0.v;
      pa[nb * 2 + 1] = f1.v;
    }

    // ka prefetch for next tile in this wave's ring (regs free after QK)
    {
      const bf16_t* kn = kfb + (size_t)((tt + 1) & 15) * 4096;
      #pragma unroll
      for (int nb = 0; nb < 2; ++nb)
        #pragma unroll
        for (int kk = 0; kk < 4; ++kk)
          ka[nb][kk] = *(const bf16x8*)(kn + (nb * 4 + kk) * 512);
    }

    // o^T += V^T . P^T (A = V^T-frag, B = P^T-frag; va pre-issued at top)
    __builtin_amdgcn_s_setprio(1);
    #pragma unroll
    for (int ks = 0; ks < 4; ++ks) {
      o0 = __builtin_amdgcn_mfma_f32_32x32x16_bf16(va0[ks], pa[ks], o0, 0, 0, 0);
      o1 = __builtin_amdgcn_mfma_f32_32x32x16_bf16(va1[ks], pa[ks], o1, 0, 0, 0);
    }
    __builtin_amdgcn_s_setprio(0);
  }

  // subtract phantom mass (p=1 per masked n, exact); fold hi halves.
  lrun -= (float)(hi ? ch : cl);
  lrun += __shfl_xor(lrun, 32);

  // ---- combine halves + transpose through LDS ----
  __syncthreads();  // first barrier in the kernel
  float* Ob = (float*)smem;                    // [64 d][128 m] f32 = 32KB
  float* Lb = (float*)(smem + 32768);          // [128] f32

  if (half == 0) {
    #pragma unroll
    for (int r = 0; r < 16; ++r) {
      const int d = (r & 3) + ((r >> 2) << 3) + (hi << 2);
      Ob[d * 128 + wq * 32 + l31]        = o0[r];
      Ob[(d + 32) * 128 + wq * 32 + l31] = o1[r];
    }
    if (hi == 0) Lb[wq * 32 + l31] = lrun;
  }
  __syncthreads();
  if (half == 1) {
    #pragma unroll
    for (int r = 0; r < 16; ++r) {
      const int d = (r & 3) + ((r >> 2) << 3) + (hi << 2);
      Ob[d * 128 + wq * 32 + l31]        += o0[r];
      Ob[(d + 32) * 128 + wq * 32 + l31] += o1[r];
    }
    if (hi == 0) Lb[wq * 32 + l31] += lrun;
  }
  __syncthreads();
  // all 512 threads: transposed read + coalesced float4 stores
  {
    const int m = tid >> 2, dc = (tid & 3) * 16;
    const float lv = Lb[m];
    const float iv = lv > 0.f ? 1.0f / lv : 0.f;
    float* orow = out + ((size_t)(b * M_ + m0 + m)) * D_ + h * DH_ + dc;
    #pragma unroll
    for (int i0 = 0; i0 < 16; i0 += 4) {
      float4 v;
      v.x = Ob[(dc + i0 + 0) * 128 + m] * iv;
      v.y = Ob[(dc + i0 + 1) * 128 + m] * iv;
      v.z = Ob[(dc + i0 + 2) * 128 + m] * iv;
      v.w = Ob[(dc + i0 + 3) * 128 + m] * iv;
      *(float4*)(orow + i0) = v;
    }
  }
}

extern "C" void kernel_launch(void* const* d_in, const int* in_sizes, int n_in,
                              void* d_out, int out_size, void* d_ws, size_t ws_size,
                              hipStream_t stream) {
  const float* q  = (const float*)d_in[0];
  const float* kv = (const float*)d_in[1];
  const int* kv_mask = (const int*)d_in[2];
  float* out = (float*)d_out;

  // ws layout: K' frags 16MB | V^T frags 16MB | maskbits 1KB
  bf16_t* kp = (bf16_t*)d_ws;
  bf16_t* vt = kp + (size_t)B_ * H_ * N_ * DH_;
  unsigned long long* mb =
      (unsigned long long*)((char*)d_ws + 2 * (size_t)B_ * H_ * N_ * DH_ * sizeof(bf16_t));

  prep_kernel<<<B_ * 32 * 8, 256, 0, stream>>>(kv, kv_mask, kp, vt, mb);
  attn_kernel<<<B_ * H_ * (M_ / 128), 512, 0, stream>>>(q, kp, vt, mb, out);
}

// Round 10
// 142.627 us; speedup vs baseline: 4.2565x; 1.4375x over previous
//
#include <hip/hip_runtime.h>
#include <hip/hip_bf16.h>
#include <cmath>
#include <stdint.h>

#define B_ 4
#define M_ 1024
#define N_ 2048
#define D_ 1024
#define H_ 16
#define DH_ 64
#define NT 64      // N tile
#define NTH 16     // tiles per half (N split 2-way inside the block)
#define PITCH 72   // prep LDS pitch (bf16)

typedef __bf16 bf16_t;
typedef __attribute__((ext_vector_type(8))) __bf16 bf16x8;
typedef __attribute__((ext_vector_type(16))) float f32x16;
typedef __attribute__((ext_vector_type(2))) float f32x2;

static __device__ __forceinline__ float silu_f(float x) {
  return x / (1.0f + __expf(-x));
}

// pack two f32 -> two bf16 in one u32 (v_cvt_pk_bf16_f32)
static __device__ __forceinline__ unsigned pk2(float a, float b) {
  union { __bf16 h[2]; unsigned u; } p;
  p.h[0] = (__bf16)a; p.h[1] = (__bf16)b;
  return p.u;
}

// async global->LDS, 16B/lane; LDS dest is wave-uniform base + lane*16
static __device__ __forceinline__ void gload16(const bf16_t* g, bf16_t* l) {
  typedef __attribute__((address_space(1))) const unsigned GU;
  typedef __attribute__((address_space(3))) unsigned LU;
  __builtin_amdgcn_global_load_lds((GU*)(const unsigned*)g, (LU*)(unsigned*)l,
                                   16, 0, 0);
}

// swap bits 2 and 3 of a row index (involution) — K-row permutation so the
// QK^T C-layout registers land directly in PV B-fragment order.
static __device__ __forceinline__ int sw23(int x) {
  return (x & ~12) | ((x & 4) << 1) | ((x & 8) >> 1);
}

// ---- prep ---- (r5 version, verified)
// K' = L2norm(silu(kv heads)), ZEROED for masked n, in MFMA A-FRAGMENT order:
//   kp elem addr = bh*131072 + (tile*8 + nb*4 + kk)*512 + (hi*32+sw23(l31))*8+j
// Vt = kv^T [bh][d][n] (linear, LDS-staged in attn), ZEROED for masked n.
// Mask bits packed for the phantom-mass correction.
__global__ __launch_bounds__(256) void prep_kernel(
    const float* __restrict__ kv, const int* __restrict__ kv_mask,
    bf16_t* __restrict__ kp, bf16_t* __restrict__ vt,
    unsigned long long* __restrict__ mb) {
  __shared__ __align__(16) bf16_t Lt[NT][PITCH];
  const int bx = blockIdx.x;
  const int hp = bx & 7;
  const int nt = (bx >> 3) & 31;
  const int b  = bx >> 8;
  const int n0 = nt * NT;
  const int tid = threadIdx.x;
  const float keep = kv_mask[b * N_ + n0 + (tid >> 2)] ? 0.f : 1.f;

  #pragma unroll
  for (int hi = 0; hi < 2; ++hi) {
    const int h = hp * 2 + hi;
    const size_t bh = (size_t)(b * H_ + h);
    {
      const int r = tid >> 2, c0 = (tid & 3) * 16;
      const float* src = kv + ((size_t)(b * N_ + n0 + r)) * D_ + h * DH_ + c0;
      union { float f[16]; float4 v4[4]; } raw;
      raw.v4[0] = *(const float4*)(src + 0);
      raw.v4[1] = *(const float4*)(src + 4);
      raw.v4[2] = *(const float4*)(src + 8);
      raw.v4[3] = *(const float4*)(src + 12);
      float sv[16];
      float ss = 0.f;
      #pragma unroll
      for (int i = 0; i < 16; ++i) { sv[i] = silu_f(raw.f[i]); ss += sv[i] * sv[i]; }
      ss += __shfl_xor(ss, 1); ss += __shfl_xor(ss, 2);
      const float inv = keep / fmaxf(sqrtf(ss), 1e-6f);  // 0 for masked rows
      union { bf16_t bs[16]; uint4 u[2]; } pk;
      #pragma unroll
      for (int i = 0; i < 16; ++i) pk.bs[i] = (bf16_t)(sv[i] * inv);
      // fragment-order K' write: kk = tid&3, nb = r>>5, lane-row sw23(r&31)
      const size_t fbase = bh * 131072 +
          (size_t)((nt * 8 + (r >> 5) * 4 + (tid & 3)) * 512 + sw23(r & 31) * 8);
      *(uint4*)(kp + fbase)       = pk.u[0];   // hi = 0 (d kk*16 + 0..7)
      *(uint4*)(kp + fbase + 256) = pk.u[1];   // hi = 1 (d kk*16 + 8..15)
      union { bf16_t bs[16]; uint4 u[2]; } pv;
      #pragma unroll
      for (int i = 0; i < 16; ++i) pv.bs[i] = (bf16_t)(raw.f[i] * keep);
      uint4* ldst = (uint4*)&Lt[r][c0];
      ldst[0] = pv.u[0]; ldst[1] = pv.u[1];
    }
    __syncthreads();
    {
      const int d = tid >> 2, nc = (tid & 3) * 16;
      union { bf16_t bs[16]; uint4 u[2]; } pk;
      #pragma unroll
      for (int i = 0; i < 16; ++i) pk.bs[i] = Lt[nc + i][d];
      uint4* dst = (uint4*)(vt + (bh * DH_ + d) * N_ + n0 + nc);
      dst[0] = pk.u[0]; dst[1] = pk.u[1];
    }
    __syncthreads();
  }
  if (bx == 0 && tid < B_ * (N_ / 64)) {
    const int b2 = tid >> 5, tt = tid & 31;
    unsigned long long m = 0ull;
    for (int i = 0; i < 64; ++i)
      if (kv_mask[b2 * N_ + tt * 64 + i]) m |= (1ull << i);
    mb[tid] = m;
  }
}

// ---- main: r5 structure VERBATIM minus s_setprio (single-variable A/B).
//      32x32x16 MFMA; K fragments register-direct (frag-order workspace,
//      prefetched one tile ahead); V LDS-staged (gload16 ping-pong, one
//      barrier per tile); poly softmax e^x ~= 1+x+x^2/2 with /8 folded into
//      Q; masked n algebraic (zeroed K'/V + popcount); 2-way N-split.
//      Theory under test: setprio(1) around MFMA clusters makes priority
//      arbitration starve softmax/load-phase waves -> waves serialize
//      (wall ~= 4 x 16 x per-tile path). Removing it should let the CU
//      interleave the 4 waves' phases. ----
__global__ __launch_bounds__(512, 4) void attn_kernel(
    const float* __restrict__ q, const bf16_t* __restrict__ kp,
    const bf16_t* __restrict__ vt, const unsigned long long* __restrict__ mb,
    float* __restrict__ out) {
  // V[half][buf] at (half*2+buf)*8192 (32KB); epilogue reuses [0,32768) for
  // O^T-partials, Lb at 32768.
  __shared__ __align__(1024) char smem[33280];

  const int tid  = threadIdx.x;
  const int w    = tid >> 6;     // 0..7
  const int wq   = w & 3;        // q-row group
  const int half = w >> 2;       // N-half
  const int lane = tid & 63;
  const int l31  = lane & 31;
  const int hi   = lane >> 5;
  const int rho  = l31 & 7;

  // bijective XCD swizzle (512 wgs % 8 == 0)
  const int wg = (blockIdx.x & 7) * 64 + (blockIdx.x >> 3);
  const int bh = wg >> 3;
  const int m0 = (wg & 7) * 128;
  const int b = bh >> 4, h = bh & 15;

  const bf16_t* vtb = vt + (size_t)bh * DH_ * N_;
  // per-lane K-fragment base: tile stride 4096 elems (8 frags x 512)
  const bf16_t* kfb = kp + (size_t)bh * 131072 + (size_t)half * 65536
                         + (size_t)lane * 8;

  // V staging: wave stages d-rows [wq*16, wq*16+16); source slot-swizzled.
  const int srow  = lane >> 3;
  const int sslot = (lane & 7) ^ srow;
  const bf16_t* vs0 = vtb + (size_t)(wq * 16 + srow) * N_ + half * NTH * NT + sslot * 8;
  const bf16_t* vs1 = vs0 + 8 * N_;

  // prologue: stage V(0); load ka(0) fragments
  {
    bf16_t* Vd = (bf16_t*)(smem + (half * 2 + 0) * 8192) + wq * 16 * NT;
    gload16(vs0, Vd); gload16(vs1, Vd + 512);
  }
  bf16x8 ka[2][4];
  #pragma unroll
  for (int nb = 0; nb < 2; ++nb)
    #pragma unroll
    for (int kk = 0; kk < 4; ++kk)
      ka[nb][kk] = *(const bf16x8*)(kfb + (nb * 4 + kk) * 512);

  // Q: 32 rows/wave straight to registers, pre-scaled by 1/8 (exact 2^-3)
  bf16x8 qb[4];
  {
    const float* qrow =
        q + ((size_t)(b * M_ + m0 + wq * 32 + l31)) * D_ + h * DH_ + hi * 8;
    float sv[32];
    float ss = 0.f;
    #pragma unroll
    for (int kk = 0; kk < 4; ++kk) {
      float4 a0 = *(const float4*)(qrow + kk * 16);
      float4 a1 = *(const float4*)(qrow + kk * 16 + 4);
      sv[kk * 8 + 0] = silu_f(a0.x); sv[kk * 8 + 1] = silu_f(a0.y);
      sv[kk * 8 + 2] = silu_f(a0.z); sv[kk * 8 + 3] = silu_f(a0.w);
      sv[kk * 8 + 4] = silu_f(a1.x); sv[kk * 8 + 5] = silu_f(a1.y);
      sv[kk * 8 + 6] = silu_f(a1.z); sv[kk * 8 + 7] = silu_f(a1.w);
      #pragma unroll
      for (int i = 0; i < 8; ++i) ss += sv[kk * 8 + i] * sv[kk * 8 + i];
    }
    ss += __shfl_xor(ss, 32);
    const float inv = 0.125f / fmaxf(sqrtf(ss), 1e-6f);
    #pragma unroll
    for (int kk = 0; kk < 4; ++kk) {
      union { unsigned u[4]; bf16x8 v; } pq;
      #pragma unroll
      for (int jj = 0; jj < 4; ++jj)
        pq.u[jj] = pk2(sv[kk * 8 + jj * 2] * inv, sv[kk * 8 + jj * 2 + 1] * inv);
      qb[kk] = pq.v;
    }
  }

  // V fragment read offsets: row = i*32+l31, slot' = (2j+hi) ^ (row&7)
  int foff[2][4];
  #pragma unroll
  for (int i = 0; i < 2; ++i)
    #pragma unroll
    for (int j = 0; j < 4; ++j)
      foff[i][j] = (i * 32 + l31) * 64 + ((((j << 1) + hi) ^ rho) << 3);

  f32x16 o0, o1, zvec;
  #pragma unroll
  for (int r = 0; r < 16; ++r) { o0[r] = 0.f; o1[r] = 0.f; zvec[r] = 0.f; }
  float lrun = 0.f;
  unsigned cl = 0, ch = 0;  // masked-n counts for hi=0 / hi=1 lanes
  const unsigned long long* mbb = mb + b * (N_ / 64);

  for (int tt = 0; tt < NTH; ++tt) {
    // barrier: (a) drains V-DMA(tt) + my ka loads (implicit vmcnt(0)),
    // (b) all waves done reading V buf cur^1 -> safe to restage
    __syncthreads();
    const int cur = tt & 1;
    if (tt + 1 < NTH) {
      const int nx = cur ^ 1;
      const size_t vo = (size_t)(tt + 1) * NT;
      bf16_t* Vd = (bf16_t*)(smem + (half * 2 + nx) * 8192) + wq * 16 * NT;
      gload16(vs0 + vo, Vd); gload16(vs1 + vo, Vd + 512);
    }
    // phantom-mass counts (uniform -> SALU popcount); with sw23 permutation
    // lane hi covers n bits {16c + 8*hi + 0..7}.
    const unsigned long long mk = mbb[half * NTH + tt];
    cl += (unsigned)__popcll(mk & 0x00FF00FF00FF00FFULL);
    ch += (unsigned)__popcll(mk & 0xFF00FF00FF00FF00ULL);

    const bf16_t* Vc = (const bf16_t*)(smem + (half * 2 + cur) * 8192);

    bf16x8 pa[4];
    #pragma unroll
    for (int nb = 0; nb < 2; ++nb) {
      // S^T = K'(permuted) . Q'^T : col = l31 (m); reg r of lane hi is
      // n_phys = 16*(r>>3) + 8*hi + (r&7) within this nb 32-block
      f32x16 s = __builtin_amdgcn_mfma_f32_32x32x16_bf16(
          ka[nb][0], qb[0], zvec, 0, 0, 0);
      #pragma unroll
      for (int kk = 1; kk < 4; ++kk)
        s = __builtin_amdgcn_mfma_f32_32x32x16_bf16(ka[nb][kk], qb[kk], s, 0, 0, 0);

      // p = e^x ~= 1 + x + x^2/2 (|x| <= 1/8); poly(0) = 1 EXACTLY
      f32x2 p2[8];
      #pragma unroll
      for (int i = 0; i < 8; ++i) {
        f32x2 x; x.x = s[2 * i]; x.y = s[2 * i + 1];
        f32x2 u = x * 0.5f + 1.0f;
        p2[i] = x * u + 1.0f;
      }
      f32x2 t0 = (p2[0] + p2[1]) + (p2[2] + p2[3]);
      f32x2 t1 = (p2[4] + p2[5]) + (p2[6] + p2[7]);
      f32x2 ts = t0 + t1;
      lrun += ts.x + ts.y;

      // P registers ARE the PV B-fragment (sw23 baked into prep)
      union { unsigned u[4]; bf16x8 v; } f0, f1;
      #pragma unroll
      for (int jj = 0; jj < 4; ++jj) {
        f0.u[jj] = pk2(p2[jj].x, p2[jj].y);
        f1.u[jj] = pk2(p2[4 + jj].x, p2[4 + jj].y);
      }
      pa[nb * 2]     = f0.v;
      pa[nb * 2 + 1] = f1.v;
    }

    // prefetch ka for next tile (wrap at 15 -> in-bounds dummy reload)
    {
      const bf16_t* kn = kfb + (size_t)((tt + 1) & 15) * 4096;
      #pragma unroll
      for (int nb = 0; nb < 2; ++nb)
        #pragma unroll
        for (int kk = 0; kk < 4; ++kk)
          ka[nb][kk] = *(const bf16x8*)(kn + (nb * 4 + kk) * 512);
    }

    // o^T += V^T . P^T : A = V^T-frag (row = d), B = P^T-frag (col = m)
    #pragma unroll
    for (int ks = 0; ks < 4; ++ks) {
      bf16x8 vb0 = *(const bf16x8*)(Vc + foff[0][ks]);
      bf16x8 vb1 = *(const bf16x8*)(Vc + foff[1][ks]);
      o0 = __builtin_amdgcn_mfma_f32_32x32x16_bf16(vb0, pa[ks], o0, 0, 0, 0);
      o1 = __builtin_amdgcn_mfma_f32_32x32x16_bf16(vb1, pa[ks], o1, 0, 0, 0);
    }
  }

  // subtract phantom mass (p=1 per masked n, exact); fold hi halves.
  lrun -= (float)(hi ? ch : cl);
  lrun += __shfl_xor(lrun, 32);

  // ---- combine halves + transpose through LDS ----
  __syncthreads();  // all V reads done; safe to reuse smem
  float* Ob = (float*)smem;                    // [64 d][128 m] f32 = 32KB
  float* Lb = (float*)(smem + 32768);          // [128] f32

  if (half == 0) {
    #pragma unroll
    for (int r = 0; r < 16; ++r) {
      const int d = (r & 3) + ((r >> 2) << 3) + (hi << 2);
      Ob[d * 128 + wq * 32 + l31]        = o0[r];
      Ob[(d + 32) * 128 + wq * 32 + l31] = o1[r];
    }
    if (hi == 0) Lb[wq * 32 + l31] = lrun;
  }
  __syncthreads();
  if (half == 1) {
    #pragma unroll
    for (int r = 0; r < 16; ++r) {
      const int d = (r & 3) + ((r >> 2) << 3) + (hi << 2);
      Ob[d * 128 + wq * 32 + l31]        += o0[r];
      Ob[(d + 32) * 128 + wq * 32 + l31] += o1[r];
    }
    if (hi == 0) Lb[wq * 32 + l31] += lrun;
  }
  __syncthreads();
  // all 512 threads: transposed read + coalesced float4 stores
  {
    const int m = tid >> 2, dc = (tid & 3) * 16;
    const float lv = Lb[m];
    const float iv = lv > 0.f ? 1.0f / lv : 0.f;
    float* orow = out + ((size_t)(b * M_ + m0 + m)) * D_ + h * DH_ + dc;
    #pragma unroll
    for (int i0 = 0; i0 < 16; i0 += 4) {
      float4 v;
      v.x = Ob[(dc + i0 + 0) * 128 + m] * iv;
      v.y = Ob[(dc + i0 + 1) * 128 + m] * iv;
      v.z = Ob[(dc + i0 + 2) * 128 + m] * iv;
      v.w = Ob[(dc + i0 + 3) * 128 + m] * iv;
      *(float4*)(orow + i0) = v;
    }
  }
}

extern "C" void kernel_launch(void* const* d_in, const int* in_sizes, int n_in,
                              void* d_out, int out_size, void* d_ws, size_t ws_size,
                              hipStream_t stream) {
  const float* q  = (const float*)d_in[0];
  const float* kv = (const float*)d_in[1];
  const int* kv_mask = (const int*)d_in[2];
  float* out = (float*)d_out;

  // ws layout: K' frags 16MB | Vt 16MB | maskbits 1KB
  bf16_t* kp = (bf16_t*)d_ws;
  bf16_t* vt = kp + (size_t)B_ * H_ * N_ * DH_;
  unsigned long long* mb =
      (unsigned long long*)((char*)d_ws + 2 * (size_t)B_ * H_ * N_ * DH_ * sizeof(bf16_t));

  prep_kernel<<<B_ * 32 * 8, 256, 0, stream>>>(kv, kv_mask, kp, vt, mb);
  attn_kernel<<<B_ * H_ * (M_ / 128), 512, 0, stream>>>(q, kp, vt, mb, out);
}